// Round 1
// baseline (4851.224 us; speedup 1.0000x reference)
//
#include <hip/hip_runtime.h>

#define ZDIM 64
#define NF 32
#define HDIM 256
#define SLEN 256
#define BATCH 1024

typedef float f32x4 __attribute__((ext_vector_type(4)));
typedef __bf16 bf16x8 __attribute__((ext_vector_type(8)));

#define MFMA __builtin_amdgcn_mfma_f32_16x16x32_bf16

// ---- ws layout (units of uint4 = 16B fragment chunks) ----
// Each slot holds the 8 bf16 one lane feeds the MFMA B operand.
#define WHH_O 0       // 64 j * 8 t * 64 l  = 32768 slots
#define WIH_O 32768   // 64 j * 64 l        =  4096
#define WOUT_O 36864  //  2 j * 8 t * 64 l  =  1024
#define WLAT_O 37888  // 32 j * 2 t * 64 l  =  4096
#define PREP1_N 41984
#define WSIG_O 65536  // 256 s * 2 j * 8 t * 64 l = 262144 slots (16MB)
#define PREP2_N 262144

__device__ __forceinline__ unsigned short f2bf(float x) {
  union { float f; unsigned int u; } v; v.f = x;
  unsigned int r = (v.u + 0x7FFFu + ((v.u >> 16) & 1u)) >> 16;  // RNE
  return (unsigned short)r;
}
__device__ __forceinline__ unsigned int pk2(float a, float b) {
  return (unsigned int)f2bf(a) | ((unsigned int)f2bf(b) << 16);
}
__device__ __forceinline__ float sigf(float x) {
  return __fdividef(1.0f, 1.0f + __expf(-x));
}
__device__ __forceinline__ float tanhf_(float x) {
  return 1.0f - __fdividef(2.0f, __expf(2.0f * x) + 1.0f);
}

// Pack W_hh / W_ih / W_out / W_lat into MFMA B-fragment order:
// slot(j,t,l) element e = W[n=j*16+(l&15)][k=t*32+8*(l>>4)+e]
__global__ void prep_weights(const float* __restrict__ Whh, const float* __restrict__ Wih,
                             const float* __restrict__ Wout, const float* __restrict__ Wlat,
                             uint4* __restrict__ ws) {
  int i = blockIdx.x * 256 + threadIdx.x;
  if (i >= PREP1_N) return;
  int l = i & 63;
  int c16 = l & 15, g4 = l >> 4;
  const float* src;
  if (i < WIH_O) {                       // W_hh: rowlen 256
    int t = (i >> 6) & 7, j = i >> 9;
    src = Whh + (j * 16 + c16) * 256 + t * 32 + 8 * g4;
  } else if (i < WOUT_O) {               // W_ih: rowlen 32, single k-tile
    int ii = i - WIH_O;
    int j = ii >> 6;
    src = Wih + (j * 16 + c16) * 32 + 8 * g4;
  } else if (i < WLAT_O) {               // W_out: rowlen 256
    int ii = i - WOUT_O;
    int t = (ii >> 6) & 7, j = ii >> 9;
    src = Wout + (j * 16 + c16) * 256 + t * 32 + 8 * g4;
  } else {                               // W_lat: rowlen 64, 2 k-tiles
    int ii = i - WLAT_O;
    int t = (ii >> 6) & 1, j = ii >> 7;
    src = Wlat + (j * 16 + c16) * 64 + t * 32 + 8 * g4;
  }
  uint4 P;
  P.x = pk2(src[0], src[1]);
  P.y = pk2(src[2], src[3]);
  P.z = pk2(src[4], src[5]);
  P.w = pk2(src[6], src[7]);
  ws[i] = P;
}

// W_sig (NF x H*S), element [f][h*256+s] -> s-major fragment slots so the
// per-step sigma GEMM reads one coalesced 16KB slice.
__global__ void prep_wsig(const float* __restrict__ Wsig, uint4* __restrict__ ws) {
  int i = blockIdx.x * 256 + threadIdx.x;
  int l = i & 63;
  int t = (i >> 6) & 7;
  int jn = (i >> 9) & 1;
  int s = i >> 10;
  int f = jn * 16 + (l & 15);
  int kb = t * 32 + 8 * (l >> 4);
  const float* src = Wsig + f * (HDIM * SLEN) + kb * SLEN + s;
  uint4 P;
  P.x = pk2(src[0 * SLEN], src[1 * SLEN]);
  P.y = pk2(src[2 * SLEN], src[3 * SLEN]);
  P.z = pk2(src[4 * SLEN], src[5 * SLEN]);
  P.w = pk2(src[6 * SLEN], src[7 * SLEN]);
  ws[WSIG_O + i] = P;
}

// Persistent LSTM scan: 64 WGs x 16 batch rows, 8 waves, 256 steps in-WG.
__global__ __launch_bounds__(512, 2) void lstm_main(
    const float* __restrict__ z, const float* __restrict__ b_lat,
    const float* __restrict__ b_ih, const float* __restrict__ b_hh,
    const float* __restrict__ b_out, const float* __restrict__ b_sig,
    const uint4* __restrict__ ws, float* __restrict__ out) {
  // h double-buffered; XOR-swizzled rows (elem-index bits 3..5 ^= row&7)
  __shared__ __align__(16) unsigned short hbuf[2][16][256];
  __shared__ __align__(16) unsigned short thbuf[16][256];
  __shared__ __align__(16) unsigned short xbuf[2][16][32];
  __shared__ __align__(16) unsigned short zb[16][64];

  const int tid = threadIdx.x;
  const int w = tid >> 6;       // wave 0..7
  const int l = tid & 63;
  const int c16 = l & 15;       // M/N fragment index
  const int g4 = l >> 4;        // k-group / row-group
  const int r0 = g4 * 4;        // first of 4 D rows owned by this lane
  const int wg = blockIdx.x;

  // persistent W_ih fragments + gate bias (addresses constant across steps)
  bf16x8 wih[8];
  float biasv[8];
#pragma unroll
  for (int q = 0; q < 8; ++q) {
    int j = q * 8 + w;
    wih[q] = *reinterpret_cast<const bf16x8*>(ws + WIH_O + j * 64 + l);
    int n = j * 16 + c16;
    biasv[q] = b_ih[n] + b_hh[n];
  }
  float bo = 0.f;
  if (w < 2) bo = b_out[w * 16 + c16];

  // ---- init: hc = z @ W_lat^T + b_lat via MFMA ----
  for (int idx = tid; idx < 16 * 64; idx += 512) {
    int m = idx >> 6, k = idx & 63;
    zb[m][k] = f2bf(z[(wg * 16 + m) * 64 + k]);
  }
  xbuf[0][tid >> 5][tid & 31] = 0;  // x0 = 0
  __syncthreads();

  float cst[2][4];
  {
    bf16x8 za0 = *reinterpret_cast<const bf16x8*>(&zb[c16][8 * g4]);
    bf16x8 za1 = *reinterpret_cast<const bf16x8*>(&zb[c16][32 + 8 * g4]);
    f32x4 a2[4];
#pragma unroll
    for (int q2 = 0; q2 < 4; ++q2) {
      int j = q2 * 8 + w;
      float bl = b_lat[j * 16 + c16];
      f32x4 a = {bl, bl, bl, bl};
      a = MFMA(za0, *reinterpret_cast<const bf16x8*>(ws + WLAT_O + (j * 2 + 0) * 64 + l), a, 0, 0, 0);
      a = MFMA(za1, *reinterpret_cast<const bf16x8*>(ws + WLAT_O + (j * 2 + 1) * 64 + l), a, 0, 0, 0);
      a2[q2] = a;
    }
    // n<256 -> h0 into LDS; n>=256 -> c0 already in exactly this lane's slots
#pragma unroll
    for (int q2 = 0; q2 < 2; ++q2) {
      int col = q2 * 128 + w * 16 + c16;
#pragma unroll
      for (int v = 0; v < 4; ++v) {
        int rr = r0 + v;
        hbuf[0][rr][col ^ ((rr & 7) << 3)] = f2bf(a2[q2][v]);
      }
    }
#pragma unroll
    for (int p = 0; p < 2; ++p)
#pragma unroll
      for (int v = 0; v < 4; ++v) cst[p][v] = a2[2 + p][v];
  }
  f32x4 sigacc = {0.f, 0.f, 0.f, 0.f};
  __syncthreads();

  // ---- the scan ----
  for (int s = 0; s < SLEN; ++s) {
    const int pb = s & 1;
    // phase 1: g = x@W_ih^T + h@W_hh^T + bias   (each wave: 8 n-tiles)
    bf16x8 afr[8];
#pragma unroll
    for (int t = 0; t < 8; ++t) {
      int kb = t * 32 + 8 * g4;
      afr[t] = *reinterpret_cast<const bf16x8*>(&hbuf[pb][c16][kb ^ ((c16 & 7) << 3)]);
    }
    bf16x8 xfr = *reinterpret_cast<const bf16x8*>(&xbuf[pb][c16][8 * g4]);
    f32x4 acc[8];
#pragma unroll
    for (int q = 0; q < 8; ++q) {
      f32x4 a = {biasv[q], biasv[q], biasv[q], biasv[q]};
      a = MFMA(xfr, wih[q], a, 0, 0, 0);
      const uint4* bp = ws + WHH_O + ((q * 8 + w) * 8) * 64 + l;
#pragma unroll
      for (int t = 0; t < 8; ++t)
        a = MFMA(afr[t], *reinterpret_cast<const bf16x8*>(bp + t * 64), a, 0, 0, 0);
      acc[q] = a;
    }
    // elementwise LSTM cell (f32 state in registers; q pairing puts i/f/g/o
    // for the same h-column in this lane)
#pragma unroll
    for (int p = 0; p < 2; ++p) {
      const int hcol = p * 128 + w * 16 + c16;
#pragma unroll
      for (int v = 0; v < 4; ++v) {
        float iv = acc[0 + p][v];
        float fv = acc[2 + p][v];
        float gv = acc[4 + p][v];
        float ov = acc[6 + p][v];
        float cc = sigf(fv) * cst[p][v] + sigf(iv) * tanhf_(gv);
        cst[p][v] = cc;
        float hh = sigf(ov) * tanhf_(cc);
        float th = tanhf_(hh);
        int rr = r0 + v;
        int sc = hcol ^ ((rr & 7) << 3);
        hbuf[pb ^ 1][rr][sc] = f2bf(hh);
        thbuf[rr][sc] = f2bf(th);
      }
    }
    __syncthreads();
    // phase 3: waves 0-1: x_next = tanh(h)@W_out^T (+mu write); waves 2-3: sigma accum
    if (w < 2) {
      f32x4 xacc = {bo, bo, bo, bo};
#pragma unroll
      for (int t = 0; t < 8; ++t) {
        bf16x8 ta = *reinterpret_cast<const bf16x8*>(
            &thbuf[c16][(t * 32 + 8 * g4) ^ ((c16 & 7) << 3)]);
        bf16x8 wb = *reinterpret_cast<const bf16x8*>(ws + WOUT_O + (w * 8 + t) * 64 + l);
        xacc = MFMA(ta, wb, xacc, 0, 0, 0);
      }
      const int f = w * 16 + c16;
#pragma unroll
      for (int v = 0; v < 4; ++v) {
        int rr = r0 + v;
        float xv = xacc[v];
        xbuf[pb ^ 1][rr][f] = f2bf(xv);
        out[(wg * 16 + rr) * (NF * SLEN) + f * SLEN + s] = xv;
      }
    } else if (w < 4) {
      const uint4* bp = ws + WSIG_O + ((s * 2 + (w - 2)) * 8) * 64 + l;
#pragma unroll
      for (int t = 0; t < 8; ++t) {
        bf16x8 ha = *reinterpret_cast<const bf16x8*>(
            &hbuf[pb ^ 1][c16][(t * 32 + 8 * g4) ^ ((c16 & 7) << 3)]);
        sigacc = MFMA(ha, *reinterpret_cast<const bf16x8*>(bp + t * 64), sigacc, 0, 0, 0);
      }
    }
    __syncthreads();
  }

  // ---- sigma epilogue ----
  if (w >= 2 && w < 4) {
    const int f = (w - 2) * 16 + c16;
    const float bs = b_sig[f];
    float* osig = out + BATCH * NF * SLEN;
#pragma unroll
    for (int v = 0; v < 4; ++v) {
      float x = sigacc[v] + bs;
      float sp = fmaxf(x, 0.0f) + log1pf(__expf(-fabsf(x)));
      osig[(wg * 16 + r0 + v) * NF + f] = sp;
    }
  }
}

extern "C" void kernel_launch(void* const* d_in, const int* in_sizes, int n_in,
                              void* d_out, int out_size, void* d_ws, size_t ws_size,
                              hipStream_t stream) {
  (void)in_sizes; (void)n_in; (void)out_size; (void)ws_size;
  const float* z     = (const float*)d_in[0];
  const float* W_lat = (const float*)d_in[1];
  const float* b_lat = (const float*)d_in[2];
  const float* W_ih  = (const float*)d_in[3];
  const float* b_ih  = (const float*)d_in[4];
  const float* W_hh  = (const float*)d_in[5];
  const float* b_hh  = (const float*)d_in[6];
  const float* W_out = (const float*)d_in[7];
  const float* b_out = (const float*)d_in[8];
  const float* W_sig = (const float*)d_in[9];
  const float* b_sig = (const float*)d_in[10];
  uint4* ws = (uint4*)d_ws;
  float* out = (float*)d_out;

  prep_weights<<<PREP1_N / 256, 256, 0, stream>>>(W_hh, W_ih, W_out, W_lat, ws);
  prep_wsig<<<PREP2_N / 256, 256, 0, stream>>>(W_sig, ws);
  lstm_main<<<64, 512, 0, stream>>>(z, b_lat, b_ih, b_hh, b_out, b_sig, ws, out);
}

// Round 3
// 4776.536 us; speedup vs baseline: 1.0156x; 1.0156x over previous
//
#include <hip/hip_runtime.h>

#define ZDIM 64
#define NF 32
#define HDIM 256
#define SLEN 256
#define BATCH 1024

typedef float f32x4 __attribute__((ext_vector_type(4)));
typedef __bf16 bf16x8 __attribute__((ext_vector_type(8)));
typedef unsigned int u32x4 __attribute__((ext_vector_type(4)));

#define MFMA __builtin_amdgcn_mfma_f32_16x16x32_bf16

// ---- ws layout (units of uint4 = 16B fragment chunks) ----
#define WHH_O 0       // 64 j * 8 t * 64 l  = 32768 slots
#define WIH_O 32768   // 64 j * 64 l        =  4096
#define WOUT_O 36864  //  2 j * 8 t * 64 l  =  1024
#define WLAT_O 37888  // 32 j * 2 t * 64 l  =  4096
#define PREP1_N 41984
#define WSIG_O 65536  // 256 s * 2 j * 8 t * 64 l = 262144 slots (4MB)
#define PREP2_N 262144

__device__ __forceinline__ unsigned short f2bf(float x) {
  union { float f; unsigned int u; } v; v.f = x;
  unsigned int r = (v.u + 0x7FFFu + ((v.u >> 16) & 1u)) >> 16;  // RNE
  return (unsigned short)r;
}
__device__ __forceinline__ unsigned int pk2(float a, float b) {
  return (unsigned int)f2bf(a) | ((unsigned int)f2bf(b) << 16);
}
__device__ __forceinline__ float sigf(float x) {
  return __fdividef(1.0f, 1.0f + __expf(-x));
}
__device__ __forceinline__ float tanhf_(float x) {
  return 1.0f - __fdividef(2.0f, __expf(2.0f * x) + 1.0f);
}

// Pack W_hh / W_ih / W_out / W_lat into MFMA B-fragment order:
// slot(j,t,l) element e = W[n=j*16+(l&15)][k=t*32+8*(l>>4)+e]
__global__ void prep_weights(const float* __restrict__ Whh, const float* __restrict__ Wih,
                             const float* __restrict__ Wout, const float* __restrict__ Wlat,
                             uint4* __restrict__ ws) {
  int i = blockIdx.x * 256 + threadIdx.x;
  if (i >= PREP1_N) return;
  int l = i & 63;
  int c16 = l & 15, g4 = l >> 4;
  const float* src;
  if (i < WIH_O) {                       // W_hh: rowlen 256
    int t = (i >> 6) & 7, j = i >> 9;
    src = Whh + (j * 16 + c16) * 256 + t * 32 + 8 * g4;
  } else if (i < WOUT_O) {               // W_ih: rowlen 32, single k-tile
    int ii = i - WIH_O;
    int j = ii >> 6;
    src = Wih + (j * 16 + c16) * 32 + 8 * g4;
  } else if (i < WLAT_O) {               // W_out: rowlen 256
    int ii = i - WOUT_O;
    int t = (ii >> 6) & 7, j = ii >> 9;
    src = Wout + (j * 16 + c16) * 256 + t * 32 + 8 * g4;
  } else {                               // W_lat: rowlen 64, 2 k-tiles
    int ii = i - WLAT_O;
    int t = (ii >> 6) & 1, j = ii >> 7;
    src = Wlat + (j * 16 + c16) * 64 + t * 32 + 8 * g4;
  }
  uint4 P;
  P.x = pk2(src[0], src[1]);
  P.y = pk2(src[2], src[3]);
  P.z = pk2(src[4], src[5]);
  P.w = pk2(src[6], src[7]);
  ws[i] = P;
}

// W_sig (NF x H*S), element [f][h*256+s] -> s-major fragment slots so the
// per-step sigma GEMM reads one coalesced 16KB slice.
__global__ void prep_wsig(const float* __restrict__ Wsig, uint4* __restrict__ ws) {
  int i = blockIdx.x * 256 + threadIdx.x;
  int l = i & 63;
  int t = (i >> 6) & 7;
  int jn = (i >> 9) & 1;
  int s = i >> 10;
  int f = jn * 16 + (l & 15);
  int kb = t * 32 + 8 * (l >> 4);
  const float* src = Wsig + f * (HDIM * SLEN) + kb * SLEN + s;
  uint4 P;
  P.x = pk2(src[0 * SLEN], src[1 * SLEN]);
  P.y = pk2(src[2 * SLEN], src[3 * SLEN]);
  P.z = pk2(src[4 * SLEN], src[5 * SLEN]);
  P.w = pk2(src[6 * SLEN], src[7 * SLEN]);
  ws[WSIG_O + i] = P;
}

// Persistent LSTM scan: 64 WGs x 16 batch rows, 8 waves, 256 steps in-WG.
// q=0..3 W_hh fragments pinned in VGPRs; q=4..7 streamed from L2 (kept
// resident by nt-loading the W_sig stream). W_ih lives in LDS.
__global__ __launch_bounds__(512, 2) void lstm_main(
    const float* __restrict__ z, const float* __restrict__ b_lat,
    const float* __restrict__ b_ih, const float* __restrict__ b_hh,
    const float* __restrict__ b_out, const float* __restrict__ b_sig,
    const uint4* __restrict__ ws, float* __restrict__ out) {
  __shared__ __align__(16) uint4 wihb[4096];                     // 64KB W_ih frags
  __shared__ __align__(16) unsigned short hbuf[2][16][256];      // 16KB (swizzled)
  __shared__ __align__(16) unsigned short thbuf[16][256];        // 8KB
  __shared__ __align__(16) unsigned short xbuf[2][16][32];
  __shared__ __align__(16) unsigned short zb[16][64];

  const int tid = threadIdx.x;
  const int w = tid >> 6;       // wave 0..7
  const int l = tid & 63;
  const int c16 = l & 15;       // M/N fragment index
  const int g4 = l >> 4;        // k-group / row-group
  const int r0 = g4 * 4;        // first of 4 D rows owned by this lane
  const int wg = blockIdx.x;

  // W_ih fragments -> LDS (reused every step by all waves)
  for (int i = tid; i < 4096; i += 512) wihb[i] = ws[WIH_O + i];

  // gate bias per owned n-column
  float biasv[8];
#pragma unroll
  for (int q = 0; q < 8; ++q) {
    int n = (q * 8 + w) * 16 + c16;
    biasv[q] = b_ih[n] + b_hh[n];
  }
  float bo = 0.f;
  if (w < 2) bo = b_out[w * 16 + c16];

  // pin W_hh q=0..3 fragments in registers for the whole scan (128 VGPR)
  bf16x8 whhr[4][8];
#pragma unroll
  for (int q = 0; q < 4; ++q)
#pragma unroll
    for (int t = 0; t < 8; ++t)
      whhr[q][t] = *reinterpret_cast<const bf16x8*>(ws + WHH_O + ((q * 8 + w) * 8 + t) * 64 + l);

  // ---- init: hc = z @ W_lat^T + b_lat via MFMA ----
  for (int idx = tid; idx < 16 * 64; idx += 512) {
    int m = idx >> 6, k = idx & 63;
    zb[m][k] = f2bf(z[(wg * 16 + m) * 64 + k]);
  }
  xbuf[0][tid >> 5][tid & 31] = 0;  // x0 = 0
  __syncthreads();

  float cst[2][4];
  {
    bf16x8 za0 = *reinterpret_cast<const bf16x8*>(&zb[c16][8 * g4]);
    bf16x8 za1 = *reinterpret_cast<const bf16x8*>(&zb[c16][32 + 8 * g4]);
    f32x4 a2[4];
#pragma unroll
    for (int q2 = 0; q2 < 4; ++q2) {
      int j = q2 * 8 + w;
      float bl = b_lat[j * 16 + c16];
      f32x4 a = {bl, bl, bl, bl};
      a = MFMA(za0, *reinterpret_cast<const bf16x8*>(ws + WLAT_O + (j * 2 + 0) * 64 + l), a, 0, 0, 0);
      a = MFMA(za1, *reinterpret_cast<const bf16x8*>(ws + WLAT_O + (j * 2 + 1) * 64 + l), a, 0, 0, 0);
      a2[q2] = a;
    }
#pragma unroll
    for (int q2 = 0; q2 < 2; ++q2) {
      int col = q2 * 128 + w * 16 + c16;
#pragma unroll
      for (int v = 0; v < 4; ++v) {
        int rr = r0 + v;
        hbuf[0][rr][col ^ ((rr & 7) << 3)] = f2bf(a2[q2][v]);
      }
    }
#pragma unroll
    for (int p = 0; p < 2; ++p)
#pragma unroll
      for (int v = 0; v < 4; ++v) cst[p][v] = a2[2 + p][v];
  }
  f32x4 sigacc = {0.f, 0.f, 0.f, 0.f};
  __syncthreads();

  // ---- the scan ----
  for (int s = 0; s < SLEN; ++s) {
    const int pb = s & 1;
    // phase 1: g = x@W_ih^T + h@W_hh^T + bias   (each wave: 8 n-tiles)
    bf16x8 afr[8];
#pragma unroll
    for (int t = 0; t < 8; ++t) {
      int kb = t * 32 + 8 * g4;
      afr[t] = *reinterpret_cast<const bf16x8*>(&hbuf[pb][c16][kb ^ ((c16 & 7) << 3)]);
    }
    bf16x8 xfr = *reinterpret_cast<const bf16x8*>(&xbuf[pb][c16][8 * g4]);
    f32x4 acc[8];
    // q=0..3: register-resident weights (no memory waits in the chain)
#pragma unroll
    for (int q = 0; q < 4; ++q) {
      f32x4 a = {biasv[q], biasv[q], biasv[q], biasv[q]};
      a = MFMA(xfr, *reinterpret_cast<const bf16x8*>(&wihb[(q * 8 + w) * 64 + l]), a, 0, 0, 0);
#pragma unroll
      for (int t = 0; t < 8; ++t)
        a = MFMA(afr[t], whhr[q][t], a, 0, 0, 0);
      acc[q] = a;
    }
    // q=4..7: streamed from L2 (compiler hoists the independent loads; the
    // register-q MFMA issue above covers the L2 latency)
#pragma unroll
    for (int q = 4; q < 8; ++q) {
      f32x4 a = {biasv[q], biasv[q], biasv[q], biasv[q]};
      a = MFMA(xfr, *reinterpret_cast<const bf16x8*>(&wihb[(q * 8 + w) * 64 + l]), a, 0, 0, 0);
      const uint4* bp = ws + WHH_O + ((q * 8 + w) * 8) * 64 + l;
#pragma unroll
      for (int t = 0; t < 8; ++t)
        a = MFMA(afr[t], *reinterpret_cast<const bf16x8*>(bp + t * 64), a, 0, 0, 0);
      acc[q] = a;
    }

    // prefetch phase-3 operands now; elementwise + barrier hide the latency.
    // W_sig is a pure stream -> nontemporal so it never evicts W_hh from L2.
    bf16x8 pf[8];
    if (w < 2) {
#pragma unroll
      for (int t = 0; t < 8; ++t)
        pf[t] = *reinterpret_cast<const bf16x8*>(ws + WOUT_O + (w * 8 + t) * 64 + l);
    } else if (w < 4) {
      const u32x4* bp = reinterpret_cast<const u32x4*>(ws + WSIG_O + ((s * 2 + (w - 2)) * 8) * 64 + l);
#pragma unroll
      for (int t = 0; t < 8; ++t)
        pf[t] = __builtin_bit_cast(bf16x8, __builtin_nontemporal_load(bp + t * 64));
    }

    // elementwise LSTM cell (f32 state in registers)
#pragma unroll
    for (int p = 0; p < 2; ++p) {
      const int hcol = p * 128 + w * 16 + c16;
#pragma unroll
      for (int v = 0; v < 4; ++v) {
        float iv = acc[0 + p][v];
        float fv = acc[2 + p][v];
        float gv = acc[4 + p][v];
        float ov = acc[6 + p][v];
        float cc = sigf(fv) * cst[p][v] + sigf(iv) * tanhf_(gv);
        cst[p][v] = cc;
        float hh = sigf(ov) * tanhf_(cc);
        float th = tanhf_(hh);
        int rr = r0 + v;
        int sc = hcol ^ ((rr & 7) << 3);
        hbuf[pb ^ 1][rr][sc] = f2bf(hh);
        thbuf[rr][sc] = f2bf(th);
      }
    }
    __syncthreads();
    // phase 3: waves 0-1: x_next = tanh(h)@W_out^T (+mu write); waves 2-3: sigma accum
    if (w < 2) {
      f32x4 xacc = {bo, bo, bo, bo};
#pragma unroll
      for (int t = 0; t < 8; ++t) {
        bf16x8 ta = *reinterpret_cast<const bf16x8*>(
            &thbuf[c16][(t * 32 + 8 * g4) ^ ((c16 & 7) << 3)]);
        xacc = MFMA(ta, pf[t], xacc, 0, 0, 0);
      }
      const int f = w * 16 + c16;
#pragma unroll
      for (int v = 0; v < 4; ++v) {
        int rr = r0 + v;
        float xv = xacc[v];
        xbuf[pb ^ 1][rr][f] = f2bf(xv);
        out[(wg * 16 + rr) * (NF * SLEN) + f * SLEN + s] = xv;
      }
    } else if (w < 4) {
#pragma unroll
      for (int t = 0; t < 8; ++t) {
        bf16x8 ha = *reinterpret_cast<const bf16x8*>(
            &hbuf[pb ^ 1][c16][(t * 32 + 8 * g4) ^ ((c16 & 7) << 3)]);
        sigacc = MFMA(ha, pf[t], sigacc, 0, 0, 0);
      }
    }
    __syncthreads();
  }

  // ---- sigma epilogue ----
  if (w >= 2 && w < 4) {
    const int f = (w - 2) * 16 + c16;
    const float bs = b_sig[f];
    float* osig = out + BATCH * NF * SLEN;
#pragma unroll
    for (int v = 0; v < 4; ++v) {
      float x = sigacc[v] + bs;
      float sp = fmaxf(x, 0.0f) + log1pf(__expf(-fabsf(x)));
      osig[(wg * 16 + r0 + v) * NF + f] = sp;
    }
  }
}

extern "C" void kernel_launch(void* const* d_in, const int* in_sizes, int n_in,
                              void* d_out, int out_size, void* d_ws, size_t ws_size,
                              hipStream_t stream) {
  (void)in_sizes; (void)n_in; (void)out_size; (void)ws_size;
  const float* z     = (const float*)d_in[0];
  const float* W_lat = (const float*)d_in[1];
  const float* b_lat = (const float*)d_in[2];
  const float* W_ih  = (const float*)d_in[3];
  const float* b_ih  = (const float*)d_in[4];
  const float* W_hh  = (const float*)d_in[5];
  const float* b_hh  = (const float*)d_in[6];
  const float* W_out = (const float*)d_in[7];
  const float* b_out = (const float*)d_in[8];
  const float* W_sig = (const float*)d_in[9];
  const float* b_sig = (const float*)d_in[10];
  uint4* ws = (uint4*)d_ws;
  float* out = (float*)d_out;

  prep_weights<<<PREP1_N / 256, 256, 0, stream>>>(W_hh, W_ih, W_out, W_lat, ws);
  prep_wsig<<<PREP2_N / 256, 256, 0, stream>>>(W_sig, ws);
  lstm_main<<<64, 512, 0, stream>>>(z, b_lat, b_ih, b_hh, b_out, b_sig, ws, out);
}

// Round 4
// 3254.965 us; speedup vs baseline: 1.4904x; 1.4675x over previous
//
#include <hip/hip_runtime.h>

#define ZDIM 64
#define NF 32
#define HDIM 256
#define SLEN 256
#define BATCH 1024

typedef float f32x4 __attribute__((ext_vector_type(4)));
typedef __bf16 bf16x8 __attribute__((ext_vector_type(8)));

#define MFMA __builtin_amdgcn_mfma_f32_16x16x32_bf16

// ---- ws layout ----
// bytes [0, 672KB):  packed MFMA B-fragments (uint4 slots, as below)
// bytes [1MB, 5MB):  Wt bf16 [32 f][65536 k], k = s*256 + h   (W_sig transposed)
// bytes [8MB, 40MB): hst bf16 [1024 b][256 s][256 h]
#define WHH_O 0       // 64 j * 8 t * 64 l  = 32768 slots
#define WIH_O 32768   // 64 j * 64 l        =  4096
#define WOUT_O 36864  //  2 j * 8 t * 64 l  =  1024
#define WLAT_O 37888  // 32 j * 2 t * 64 l  =  4096
#define PREP1_N 41984
#define WT_BYTE (1 << 20)
#define HST_BYTE (8 << 20)

__device__ __forceinline__ unsigned short f2bf(float x) {
  union { float f; unsigned int u; } v; v.f = x;
  unsigned int r = (v.u + 0x7FFFu + ((v.u >> 16) & 1u)) >> 16;  // RNE
  return (unsigned short)r;
}
__device__ __forceinline__ unsigned int pk2(float a, float b) {
  return (unsigned int)f2bf(a) | ((unsigned int)f2bf(b) << 16);
}
__device__ __forceinline__ float sigf(float x) {
  return __fdividef(1.0f, 1.0f + __expf(-x));
}
__device__ __forceinline__ float tanhf_(float x) {
  return 1.0f - __fdividef(2.0f, __expf(2.0f * x) + 1.0f);
}

// Pack W_hh / W_ih / W_out / W_lat into MFMA B-fragment order:
// slot(j,t,l) element e = W[n=j*16+(l&15)][k=t*32+8*(l>>4)+e]
__global__ void prep_weights(const float* __restrict__ Whh, const float* __restrict__ Wih,
                             const float* __restrict__ Wout, const float* __restrict__ Wlat,
                             uint4* __restrict__ ws) {
  int i = blockIdx.x * 256 + threadIdx.x;
  if (i >= PREP1_N) return;
  int l = i & 63;
  int c16 = l & 15, g4 = l >> 4;
  const float* src;
  if (i < WIH_O) {                       // W_hh: rowlen 256
    int t = (i >> 6) & 7, j = i >> 9;
    src = Whh + (j * 16 + c16) * 256 + t * 32 + 8 * g4;
  } else if (i < WOUT_O) {               // W_ih: rowlen 32, single k-tile
    int ii = i - WIH_O;
    int j = ii >> 6;
    src = Wih + (j * 16 + c16) * 32 + 8 * g4;
  } else if (i < WLAT_O) {               // W_out: rowlen 256
    int ii = i - WOUT_O;
    int t = (ii >> 6) & 7, j = ii >> 9;
    src = Wout + (j * 16 + c16) * 256 + t * 32 + 8 * g4;
  } else {                               // W_lat: rowlen 64, 2 k-tiles
    int ii = i - WLAT_O;
    int t = (ii >> 6) & 1, j = ii >> 7;
    src = Wlat + (j * 16 + c16) * 64 + t * 32 + 8 * g4;
  }
  uint4 P;
  P.x = pk2(src[0], src[1]);
  P.y = pk2(src[2], src[3]);
  P.z = pk2(src[4], src[5]);
  P.w = pk2(src[6], src[7]);
  ws[i] = P;
}

// Transpose W_sig [32 f][h*256+s] (f32) -> Wt [32 f][s*256+h] (bf16).
// WG = (f, hblk of 32). Coalesced reads (along s), coalesced 64B writes (along h).
__global__ void prep_wt(const float* __restrict__ Wsig, unsigned short* __restrict__ Wt) {
  __shared__ float tile[32][257];
  int f = blockIdx.x >> 3, hb = blockIdx.x & 7;
  int tid = threadIdx.x;  // 256
  const float* src = Wsig + f * (HDIM * SLEN) + hb * 32 * 256;
#pragma unroll
  for (int i = 0; i < 32; ++i) {
    tile[i][tid] = src[i * 256 + tid];
  }
  __syncthreads();
  int s = tid;
  unsigned short tmp[32];
#pragma unroll
  for (int h = 0; h < 32; ++h) tmp[h] = f2bf(tile[h][s]);
  uint4* dst = (uint4*)(Wt + f * 65536 + s * 256 + hb * 32);
  const uint4* tsrc = (const uint4*)tmp;
#pragma unroll
  for (int j = 0; j < 4; ++j) dst[j] = tsrc[j];
}

// Persistent LSTM scan: 64 WGs x 16 batch rows, 8 waves, 256 steps in-WG.
// No W_sig here. mu buffered in LDS, flushed every 16 steps as full lines.
// h_s stored coalesced (bf16) to hst for the separate sigma GEMM.
__global__ __launch_bounds__(512) void lstm_scan(
    const float* __restrict__ z, const float* __restrict__ b_lat,
    const float* __restrict__ b_ih, const float* __restrict__ b_hh,
    const float* __restrict__ b_out,
    const uint4* __restrict__ ws, unsigned short* __restrict__ hst,
    float* __restrict__ out) {
  __shared__ __align__(16) uint4 wihb[4096];                     // 64KB W_ih frags
  __shared__ __align__(16) uint4 woutb[1024];                    // 16KB W_out frags
  __shared__ __align__(16) unsigned short hbuf[2][16][256];      // 16KB (swizzled)
  __shared__ __align__(16) unsigned short thbuf[16][256];        // 8KB
  __shared__ __align__(16) unsigned short xbuf[2][16][32];       // 2KB
  __shared__ __align__(16) float mubuf[16][16][32];              // 32KB
  __shared__ __align__(16) unsigned short zb[16][64];            // 2KB

  const int tid = threadIdx.x;
  const int w = tid >> 6;       // wave 0..7
  const int l = tid & 63;
  const int c16 = l & 15;       // M/N fragment index
  const int g4 = l >> 4;        // k-group / row-group
  const int r0 = g4 * 4;        // first of 4 D rows owned by this lane
  const int wg = blockIdx.x;

  // W_ih + W_out fragments -> LDS (reused every step)
  for (int i = tid; i < 4096; i += 512) wihb[i] = ws[WIH_O + i];
  for (int i = tid; i < 1024; i += 512) woutb[i] = ws[WOUT_O + i];

  // gate bias per owned n-column
  float biasv[8];
#pragma unroll
  for (int q = 0; q < 8; ++q) {
    int n = (q * 8 + w) * 16 + c16;
    biasv[q] = b_ih[n] + b_hh[n];
  }
  float bo = 0.f;
  if (w < 2) bo = b_out[w * 16 + c16];

  // ---- init: hc = z @ W_lat^T + b_lat via MFMA ----
  for (int idx = tid; idx < 16 * 64; idx += 512) {
    int m = idx >> 6, k = idx & 63;
    zb[m][k] = f2bf(z[(wg * 16 + m) * 64 + k]);
  }
  xbuf[0][tid >> 5][tid & 31] = 0;  // x0 = 0
  __syncthreads();

  float cst[2][4];
  {
    bf16x8 za0 = *reinterpret_cast<const bf16x8*>(&zb[c16][8 * g4]);
    bf16x8 za1 = *reinterpret_cast<const bf16x8*>(&zb[c16][32 + 8 * g4]);
    f32x4 a2[4];
#pragma unroll
    for (int q2 = 0; q2 < 4; ++q2) {
      int j = q2 * 8 + w;
      float bl = b_lat[j * 16 + c16];
      f32x4 a = {bl, bl, bl, bl};
      a = MFMA(za0, *reinterpret_cast<const bf16x8*>(ws + WLAT_O + (j * 2 + 0) * 64 + l), a, 0, 0, 0);
      a = MFMA(za1, *reinterpret_cast<const bf16x8*>(ws + WLAT_O + (j * 2 + 1) * 64 + l), a, 0, 0, 0);
      a2[q2] = a;
    }
#pragma unroll
    for (int q2 = 0; q2 < 2; ++q2) {
      int col = q2 * 128 + w * 16 + c16;
#pragma unroll
      for (int v = 0; v < 4; ++v) {
        int rr = r0 + v;
        hbuf[0][rr][col ^ ((rr & 7) << 3)] = f2bf(a2[q2][v]);
      }
    }
#pragma unroll
    for (int p = 0; p < 2; ++p)
#pragma unroll
      for (int v = 0; v < 4; ++v) cst[p][v] = a2[2 + p][v];
  }
  __syncthreads();

  // ---- the scan ----
  for (int s = 0; s < SLEN; ++s) {
    const int pb = s & 1;
    // phase 1: g = x@W_ih^T + h@W_hh^T + bias   (each wave: 8 n-tiles)
    bf16x8 afr[8];
#pragma unroll
    for (int t = 0; t < 8; ++t) {
      int kb = t * 32 + 8 * g4;
      afr[t] = *reinterpret_cast<const bf16x8*>(&hbuf[pb][c16][kb ^ ((c16 & 7) << 3)]);
    }
    bf16x8 xfr = *reinterpret_cast<const bf16x8*>(&xbuf[pb][c16][8 * g4]);
    f32x4 acc[8];
#pragma unroll
    for (int q = 0; q < 8; ++q) {
      f32x4 a = {biasv[q], biasv[q], biasv[q], biasv[q]};
      a = MFMA(xfr, *reinterpret_cast<const bf16x8*>(&wihb[(q * 8 + w) * 64 + l]), a, 0, 0, 0);
      const uint4* bp = ws + WHH_O + ((q * 8 + w) * 8) * 64 + l;
#pragma unroll
      for (int t = 0; t < 8; ++t)
        a = MFMA(afr[t], *reinterpret_cast<const bf16x8*>(bp + t * 64), a, 0, 0, 0);
      acc[q] = a;
    }

    // elementwise LSTM cell (f32 state in registers)
#pragma unroll
    for (int p = 0; p < 2; ++p) {
      const int hcol = p * 128 + w * 16 + c16;
#pragma unroll
      for (int v = 0; v < 4; ++v) {
        float iv = acc[0 + p][v];
        float fv = acc[2 + p][v];
        float gv = acc[4 + p][v];
        float ov = acc[6 + p][v];
        float cc = sigf(fv) * cst[p][v] + sigf(iv) * tanhf_(gv);
        cst[p][v] = cc;
        float hh = sigf(ov) * tanhf_(cc);
        float th = tanhf_(hh);
        int rr = r0 + v;
        int sc = hcol ^ ((rr & 7) << 3);
        hbuf[pb ^ 1][rr][sc] = f2bf(hh);
        thbuf[rr][sc] = f2bf(th);
      }
    }
    __syncthreads();
    // phase 3: waves 0-1: x_next = tanh(h)@W_out^T -> xbuf + mu into LDS;
    //          waves 4-7: copy h_{s+1} (unswizzled) -> hst global, coalesced.
    if (w < 2) {
      f32x4 xacc = {bo, bo, bo, bo};
#pragma unroll
      for (int t = 0; t < 8; ++t) {
        bf16x8 ta = *reinterpret_cast<const bf16x8*>(
            &thbuf[c16][(t * 32 + 8 * g4) ^ ((c16 & 7) << 3)]);
        xacc = MFMA(ta, *reinterpret_cast<const bf16x8*>(&woutb[(w * 8 + t) * 64 + l]), xacc, 0, 0, 0);
      }
      const int f = w * 16 + c16;
      const int sw = s & 15;
#pragma unroll
      for (int v = 0; v < 4; ++v) {
        int rr = r0 + v;
        float xv = xacc[v];
        xbuf[pb ^ 1][rr][f] = f2bf(xv);
        mubuf[sw][rr][f] = xv;
      }
    } else if (w >= 4) {
      int t4 = tid - 256;
#pragma unroll
      for (int rep = 0; rep < 2; ++rep) {
        int task = t4 + rep * 256;
        int r = task >> 5;
        int h0 = (task & 31) * 8;
        uint4 d = *reinterpret_cast<const uint4*>(&hbuf[pb ^ 1][r][h0 ^ ((r & 7) << 3)]);
        *reinterpret_cast<uint4*>(hst + ((wg * 16 + r) << 16) + (s << 8) + h0) = d;
      }
    }
    __syncthreads();
    if ((s & 15) == 15) {
      // flush 16 steps of mu: thread (b,f) writes 16 consecutive s -> 64B line
      int b = tid >> 5, f = tid & 31;
      float* dst = out + ((wg * 16 + b) << 13) + (f << 8) + (s - 15);
#pragma unroll
      for (int j4 = 0; j4 < 4; ++j4) {
        f32x4 vv;
#pragma unroll
        for (int jj = 0; jj < 4; ++jj) vv[jj] = mubuf[j4 * 4 + jj][b][f];
        *reinterpret_cast<f32x4*>(dst + j4 * 4) = vv;
      }
      // no extra barrier needed: mubuf is next written after the mid-step
      // barrier of step s+1, which orders all flush reads before it.
    }
  }
}

// sigma = softplus(hs_flat @ W_sig^T + b_sig)
// 256 WGs x 4 batch rows (A rows replicated 4x into the 16-row MFMA M dim).
// Each wave owns a 8192-wide k-chunk (32 s values); LDS cross-wave reduce.
__global__ __launch_bounds__(512) void sigma_gemm(
    const unsigned short* __restrict__ hst, const unsigned short* __restrict__ Wt,
    const float* __restrict__ b_sig, float* __restrict__ out) {
  __shared__ float sred[8][16][32];  // 16KB
  const int tid = threadIdx.x;
  const int w = tid >> 6;
  const int l = tid & 63;
  const int c16 = l & 15;
  const int g4 = l >> 4;
  const int wg = blockIdx.x;

  const unsigned short* ap =
      hst + (((wg << 2) + (c16 & 3)) << 16) + ((w * 32) << 8) + (g4 << 3);
  const unsigned short* bp0 = Wt + (c16 << 16) + ((w * 32) << 8) + (g4 << 3);
  const unsigned short* bp1 = Wt + ((16 + c16) << 16) + ((w * 32) << 8) + (g4 << 3);

  f32x4 a0 = {0.f, 0.f, 0.f, 0.f}, a1 = {0.f, 0.f, 0.f, 0.f};
#pragma unroll 8
  for (int kk = 0; kk < 256; ++kk) {
    int off = ((kk >> 3) << 8) + ((kk & 7) << 5);
    bf16x8 av = *reinterpret_cast<const bf16x8*>(ap + off);
    a0 = MFMA(av, *reinterpret_cast<const bf16x8*>(bp0 + off), a0, 0, 0, 0);
    a1 = MFMA(av, *reinterpret_cast<const bf16x8*>(bp1 + off), a1, 0, 0, 0);
  }
#pragma unroll
  for (int v = 0; v < 4; ++v) {
    sred[w][g4 * 4 + v][c16] = a0[v];
    sred[w][g4 * 4 + v][16 + c16] = a1[v];
  }
  __syncthreads();
  int b = tid >> 5, f = tid & 31;
  if (b < 4) {
    float acc = b_sig[f];
#pragma unroll
    for (int ww = 0; ww < 8; ++ww) acc += sred[ww][b][f];
    float sp = fmaxf(acc, 0.0f) + log1pf(__expf(-fabsf(acc)));
    out[BATCH * NF * SLEN + ((wg << 2) + b) * NF + f] = sp;
  }
}

extern "C" void kernel_launch(void* const* d_in, const int* in_sizes, int n_in,
                              void* d_out, int out_size, void* d_ws, size_t ws_size,
                              hipStream_t stream) {
  (void)in_sizes; (void)n_in; (void)out_size; (void)ws_size;
  const float* z     = (const float*)d_in[0];
  const float* W_lat = (const float*)d_in[1];
  const float* b_lat = (const float*)d_in[2];
  const float* W_ih  = (const float*)d_in[3];
  const float* b_ih  = (const float*)d_in[4];
  const float* W_hh  = (const float*)d_in[5];
  const float* b_hh  = (const float*)d_in[6];
  const float* W_out = (const float*)d_in[7];
  const float* b_out = (const float*)d_in[8];
  const float* W_sig = (const float*)d_in[9];
  const float* b_sig = (const float*)d_in[10];
  uint4* ws = (uint4*)d_ws;
  unsigned short* Wt  = (unsigned short*)((char*)d_ws + WT_BYTE);
  unsigned short* hst = (unsigned short*)((char*)d_ws + HST_BYTE);
  float* out = (float*)d_out;

  prep_weights<<<(PREP1_N + 255) / 256, 256, 0, stream>>>(W_hh, W_ih, W_out, W_lat, ws);
  prep_wt<<<256, 256, 0, stream>>>(W_sig, Wt);
  lstm_scan<<<64, 512, 0, stream>>>(z, b_lat, b_ih, b_hh, b_out, ws, hst, out);
  sigma_gemm<<<256, 512, 0, stream>>>(hst, Wt, b_sig, out);
}